// Round 17
// baseline (178.403 us; speedup 1.0000x reference)
//
#include <hip/hip_runtime.h>

typedef short short8  __attribute__((ext_vector_type(8)));
typedef short short4v __attribute__((ext_vector_type(4)));
typedef float f32x4   __attribute__((ext_vector_type(4)));
typedef int   i32x4   __attribute__((ext_vector_type(4)));

#define NB 4
#define NS 4096
#define NE 1024
#define ND 64

__device__ __forceinline__ short f2bf(float f) {
    unsigned u = __builtin_bit_cast(unsigned, f);
    u = (u + 0x7FFFu + ((u >> 16) & 1u)) >> 16;
    return (short)u;
}
__device__ __forceinline__ float bf2f(short s) {
    unsigned u = ((unsigned)(unsigned short)s) << 16;
    return __builtin_bit_cast(float, u);
}

// ---- kernel 1: W transpose + concat + bf16 hi/lo split (scale folded into W_Q) ----
__global__ void prep_wt(const float* __restrict__ WQ, const float* __restrict__ WK,
                        const float* __restrict__ WV,
                        short* __restrict__ wthi, short* __restrict__ wtlo) {
    int idx = blockIdx.x * 256 + threadIdx.x;     // 192*1024
    if (idx >= 192 * NE) return;
    int n = idx >> 10, k = idx & (NE - 1);
    int sel = n >> 6, d = n & 63;
    const float* W = (sel == 0) ? WQ : (sel == 1 ? WK : WV);
    float v = W[k * ND + d];
    if (sel == 0) v *= 0.125f;                    // 1/sqrt(64), exact power of 2
    short hi = f2bf(v);
    short lo = f2bf(v - bf2f(hi));
    wthi[idx] = hi;
    wtlo[idx] = lo;
}

// ---- kernel 2: QKV projection — r15 structure (register ping-pong, unroll 1,
//      XCD-pin) with BM 16: 4096 one-wave blocks = 4 waves/SIMD. TLP covers the
//      latency that regalloc-collapsed prefetch cannot (attn-proven mechanism).
//      r16's asm-vmcnt gll pipeline REVERTED (regressed: compiler B-waits drained it). ----
__global__ __launch_bounds__(64, 4) void proj_rope(
        const float* __restrict__ x,
        const short* __restrict__ wthi, const short* __restrict__ wtlo,
        short* __restrict__ qhi, short* __restrict__ qlo,
        short* __restrict__ khi, short* __restrict__ klo,
        short* __restrict__ vtb) {
    const int lane = threadIdx.x;
    const int g = lane >> 4, cl = lane & 15;
    const int bid = blockIdx.x;
    const int rtile = ((bid >> 5) << 3) | (bid & 7);   // 0..1023 (XCD-pin: col-mates +8)
    const int rb = rtile << 4;                         // 16-row tile
    const int c0 = ((bid >> 3) & 3) * 48;              // 48-col tile

    f32x4 acc[3];
    acc[0] = acc[1] = acc[2] = (f32x4){0.f, 0.f, 0.f, 0.f};

    const float* xb  = x    + (size_t)(rb + cl) * NE + (g << 3);
    const short* bh0 = wthi + (size_t)(c0 + cl) * NE + (g << 3);
    const short* bl0 = wtlo + (size_t)(c0 + cl) * NE + (g << 3);

    float4 x0[2], x1[2];          // ping-pong x slots (one 16-row tile each)
    short8 b0[6], b1[6];          // ping-pong B slots: [ct*2 + (hi/lo)]

#define LOADX(Xs, kk) {                                                      \
        const float* xp = xb + (kk);                                         \
        Xs[0] = *(const float4*)(xp);                                        \
        Xs[1] = *(const float4*)(xp + 4); }
#define LOADB(Bs, kk) {                                                      \
        _Pragma("unroll")                                                    \
        for (int ct = 0; ct < 3; ++ct) {                                     \
            Bs[ct * 2]     = *(const short8*)(bh0 + (ct << 4) * NE + (kk));  \
            Bs[ct * 2 + 1] = *(const short8*)(bl0 + (ct << 4) * NE + (kk));  \
        } }
#define STAGE(Xs, Bs) {                                                      \
        short8 ah, al;                                                       \
        float vv[8] = {Xs[0].x, Xs[0].y, Xs[0].z, Xs[0].w,                   \
                       Xs[1].x, Xs[1].y, Xs[1].z, Xs[1].w};                  \
        _Pragma("unroll")                                                    \
        for (int q = 0; q < 8; ++q) {                                        \
            short h = f2bf(vv[q]);                                           \
            ah[q] = h;                                                       \
            al[q] = f2bf(vv[q] - bf2f(h));                                   \
        }                                                                    \
        _Pragma("unroll")                                                    \
        for (int ct = 0; ct < 3; ++ct) {                                     \
            acc[ct] = __builtin_amdgcn_mfma_f32_16x16x32_bf16(ah, Bs[ct*2],   acc[ct], 0, 0, 0); \
            acc[ct] = __builtin_amdgcn_mfma_f32_16x16x32_bf16(ah, Bs[ct*2+1], acc[ct], 0, 0, 0); \
            acc[ct] = __builtin_amdgcn_mfma_f32_16x16x32_bf16(al, Bs[ct*2],   acc[ct], 0, 0, 0); \
        } }

    LOADX(x0, 0); LOADX(x1, 32);
    LOADB(b0, 0); LOADB(b1, 32);

    #pragma unroll 1
    for (int k0 = 0; k0 < NE; k0 += 64) {
        STAGE(x0, b0);
        if (k0 + 64 < NE) { LOADX(x0, k0 + 64); LOADB(b0, k0 + 64); }
        STAGE(x1, b1);
        if (k0 + 96 < NE) { LOADX(x1, k0 + 96); LOADB(b1, k0 + 96); }
    }
#undef LOADX
#undef LOADB
#undef STAGE

    // epilogue: RoPE (fp32) + hi/lo split stores (16-row tile)
    #pragma unroll
    for (int ct = 0; ct < 3; ++ct) {
        int c = c0 + (ct << 4) + cl;
        #pragma unroll
        for (int r = 0; r < 4; ++r) {
            int row = rb + (g << 2) + r;
            int s = row & (NS - 1);
            int b = row >> 12;
            float val = acc[ct][r];
            if (c < 128) {
                int d = c & 63;
                int p = d >> 1;
                float freq = exp2f(-(float)p * 0.41524101186091903f);
                float theta = (float)s * freq;
                float sn = sinf(theta), cs = cosf(theta);
                float partner = __shfl_xor(val, 1);
                float rot = (c & 1) ? fmaf(partner, sn, val * cs)
                                    : fmaf(-partner, sn, val * cs);
                short hi = f2bf(rot);
                short lo = f2bf(rot - bf2f(hi));
                int off = row * ND + d;
                if (c < 64) { qhi[off] = hi; qlo[off] = lo; }
                else        { khi[off] = hi; klo[off] = lo; }
            } else {
                int d = c - 128;
                vtb[(b << 18) + ((s >> 5) << 11) + (d << 5) + (s & 31)] = f2bf(val);
            }
        }
    }
}

// ---- kernel 3: causal flash attention — UNCHANGED from round 11 (validated, ~30us) ----
__global__ __launch_bounds__(256) void attn_fused(
        const short* __restrict__ qhi, const short* __restrict__ qlo,
        const short* __restrict__ khi, const short* __restrict__ klo,
        const short* __restrict__ vtb, float* __restrict__ outp) {
    __shared__ char sm[54272];
    const int tid = threadIdx.x;
    const int lane = tid & 63, w = tid >> 6;
    const int g = lane >> 4, cl = lane & 15;
    const int bid = blockIdx.x;
    const int b = (bid >> 1) & 3;
    const int t = 255 - (((bid >> 3) << 1) | (bid & 1));
    const int qw = t << 4;
    const int rowb = b << 12;

    char* SW  = sm + w * 12288;
    short* Ps = (short*)(sm + 49152 + w * 1280);

    short8 qh[2], ql[2];
    #pragma unroll
    for (int ks = 0; ks < 2; ++ks) {
        int off = ((rowb + qw + cl) << 6) + (ks << 5) + (g << 3);
        qh[ks] = *(const short8*)(qhi + off);
        ql[ks] = *(const short8*)(qlo + off);
    }

    f32x4 o[4];
    #pragma unroll
    for (int i = 0; i < 4; ++i) o[i] = (f32x4){0.f, 0.f, 0.f, 0.f};
    float m = -1e38f, lsp = 0.f;

    const int nkv = (t >> 1) + 1;
    const short* kpB = khi + (rowb << 6);
    const short* lpB = klo + (rowb << 6);
    const short* vpB = vtb + (b << 18);

    i32x4 stK[4], stL[4], stV[4];
#define ISSUE(jj) {                                                          \
        const short* kp = kpB + ((jj) << 11);                                \
        const short* lp = lpB + ((jj) << 11);                                \
        const short* vp = vpB + ((jj) << 11);                                \
        _Pragma("unroll")                                                    \
        for (int i = 0; i < 4; ++i) {                                        \
            stK[i] = *(const i32x4*)(kp + (lane << 3) + (i << 9));           \
            stL[i] = *(const i32x4*)(lp + (lane << 3) + (i << 9));           \
            stV[i] = *(const i32x4*)(vp + (lane << 3) + (i << 9));           \
        } }

    if (w < nkv) {
        ISSUE(w);
        #pragma unroll 1
        for (int j = w; j < nkv; j += 4) {
            #pragma unroll
            for (int i = 0; i < 4; ++i) {
                int c = lane + (i << 6);
                int kr = c >> 3, kc = c & 7;
                int koff = (kr << 7) + ((kc ^ (kr & 7)) << 4);
                *(i32x4*)(SW + koff) = stK[i];
                *(i32x4*)(SW + 4096 + koff) = stL[i];
                int vr = c >> 2, vc = c & 3;
                *(i32x4*)(SW + 8192 + (vr << 6) + ((vc ^ (vr & 3)) << 4)) = stV[i];
            }
            int jn = j + 4;
            if (jn < nkv) ISSUE(jn);

            f32x4 sc[2];
            #pragma unroll
            for (int ci = 0; ci < 2; ++ci) {
                const int rbase = ((ci << 4) + cl) << 7;
                const int sw = (cl & 7) << 4;
                short8 kh0 = *(short8*)(SW + rbase + (((g << 4)     ) ^ sw));
                short8 kh1 = *(short8*)(SW + rbase + (((g << 4) + 64) ^ sw));
                short8 kl0 = *(short8*)(SW + 4096 + rbase + (((g << 4)     ) ^ sw));
                short8 kl1 = *(short8*)(SW + 4096 + rbase + (((g << 4) + 64) ^ sw));
                f32x4 s = (f32x4){0.f, 0.f, 0.f, 0.f};
                s = __builtin_amdgcn_mfma_f32_16x16x32_bf16(kh0, qh[0], s, 0, 0, 0);
                s = __builtin_amdgcn_mfma_f32_16x16x32_bf16(kh1, qh[1], s, 0, 0, 0);
                s = __builtin_amdgcn_mfma_f32_16x16x32_bf16(kh0, ql[0], s, 0, 0, 0);
                s = __builtin_amdgcn_mfma_f32_16x16x32_bf16(kh1, ql[1], s, 0, 0, 0);
                s = __builtin_amdgcn_mfma_f32_16x16x32_bf16(kl0, qh[0], s, 0, 0, 0);
                s = __builtin_amdgcn_mfma_f32_16x16x32_bf16(kl1, qh[1], s, 0, 0, 0);
                sc[ci] = s;
            }
            if (j == nkv - 1) {
                #pragma unroll
                for (int ci = 0; ci < 2; ++ci)
                    #pragma unroll
                    for (int r = 0; r < 4; ++r)
                        if ((j << 5) + (ci << 4) + (g << 2) + r > qw + cl) sc[ci][r] = -1e30f;
            }
            float pm = fmaxf(fmaxf(fmaxf(sc[0][0], sc[0][1]), fmaxf(sc[0][2], sc[0][3])),
                             fmaxf(fmaxf(sc[1][0], sc[1][1]), fmaxf(sc[1][2], sc[1][3])));
            pm = fmaxf(pm, __shfl_xor(pm, 16));
            pm = fmaxf(pm, __shfl_xor(pm, 32));
            const float mo = m;
            m = fmaxf(m, pm);
            const float rs = __expf(mo - m);
            float psum = 0.f;
            #pragma unroll
            for (int ci = 0; ci < 2; ++ci) {
                float p0 = __expf(sc[ci][0] - m), p1 = __expf(sc[ci][1] - m);
                float p2 = __expf(sc[ci][2] - m), p3 = __expf(sc[ci][3] - m);
                psum += (p0 + p1) + (p2 + p3);
                short4v pk;
                pk[0] = f2bf(p0); pk[1] = f2bf(p1); pk[2] = f2bf(p2); pk[3] = f2bf(p3);
                *(short4v*)(Ps + cl * 40 + (ci << 4) + (g << 2)) = pk;
            }
            lsp = lsp * rs + psum;
            if (__any(m > mo)) {
                float rs4[4];
                #pragma unroll
                for (int r = 0; r < 4; ++r) rs4[r] = __shfl(rs, (g << 2) + r);
                #pragma unroll
                for (int dt = 0; dt < 4; ++dt)
                    #pragma unroll
                    for (int r = 0; r < 4; ++r) o[dt][r] *= rs4[r];
            }
            short8 pa = *(short8*)(Ps + cl * 40 + (g << 3));
            #pragma unroll
            for (int dt = 0; dt < 4; ++dt) {
                int vrow = (dt << 4) + cl;
                short8 vf = *(short8*)(SW + 8192 + (vrow << 6)
                                        + (((g << 4)) ^ ((vrow & 3) << 4)));
                o[dt] = __builtin_amdgcn_mfma_f32_16x16x32_bf16(pa, vf, o[dt], 0, 0, 0);
            }
        }
    }
#undef ISSUE

    {
        float* Co = (float*)SW;
        #pragma unroll
        for (int dt = 0; dt < 4; ++dt)
            #pragma unroll
            for (int r = 0; r < 4; ++r)
                Co[((g << 2) + r) * 66 + (dt << 4) + cl] = o[dt][r];
        lsp += __shfl_xor(lsp, 16);
        lsp += __shfl_xor(lsp, 32);
        if (g == 0) {
            *(float*)(SW + 4224 + (cl << 2)) = m;
            *(float*)(SW + 4288 + (cl << 2)) = lsp;
        }
    }
    __syncthreads();

    if (w == 0) {
        #pragma unroll
        for (int r = 0; r < 4; ++r) {
            const int row = (g << 2) + r;
            float mv[4], lv[4];
            #pragma unroll
            for (int v = 0; v < 4; ++v) {
                mv[v] = *(const float*)(sm + v * 12288 + 4224 + (row << 2));
                lv[v] = *(const float*)(sm + v * 12288 + 4288 + (row << 2));
            }
            float M = fmaxf(fmaxf(mv[0], mv[1]), fmaxf(mv[2], mv[3]));
            float e[4];
            float L = 0.f;
            #pragma unroll
            for (int v = 0; v < 4; ++v) { e[v] = __expf(mv[v] - M); L += lv[v] * e[v]; }
            float inv = 1.f / L;
            #pragma unroll
            for (int dt = 0; dt < 4; ++dt) {
                int d = (dt << 4) + cl;
                float O = 0.f;
                #pragma unroll
                for (int v = 0; v < 4; ++v)
                    O += ((const float*)(sm + v * 12288))[row * 66 + d] * e[v];
                outp[(rowb + qw + row) * ND + d] = O * inv;
            }
        }
    }
}

extern "C" void kernel_launch(void* const* d_in, const int* in_sizes, int n_in,
                              void* d_out, int out_size, void* d_ws, size_t ws_size,
                              hipStream_t stream) {
    const float* x  = (const float*)d_in[0];
    // d_in[1] = mask (int32 tril) -- causal structure known, unused
    const float* WQ = (const float*)d_in[2];
    const float* WK = (const float*)d_in[3];
    const float* WV = (const float*)d_in[4];

    const size_t need = 786432u + 4u * 2097152u + 2097152u;   // 11,272,192 B
    if (ws_size < need) return;

    char* ws = (char*)d_ws;
    short* wthi = (short*)(ws);                                  // 384 KB
    short* wtlo = (short*)(ws + 393216);
    short* qhi  = (short*)(ws + 786432);                         // 2 MB each
    short* qlo  = (short*)(ws + 786432 + 1 * 2097152);
    short* khi  = (short*)(ws + 786432 + 2 * 2097152);
    short* klo  = (short*)(ws + 786432 + 3 * 2097152);
    short* vtb  = (short*)(ws + 786432 + 4 * 2097152);           // V^T tile-blocked [B][128][64][32]

    prep_wt<<<768, 256, 0, stream>>>(WQ, WK, WV, wthi, wtlo);
    proj_rope<<<4096, 64, 0, stream>>>(x, wthi, wtlo, qhi, qlo, khi, klo, vtb);
    attn_fused<<<1024, 256, 0, stream>>>(qhi, qlo, khi, klo, vtb, (float*)d_out);
}

// Round 18
// 116.342 us; speedup vs baseline: 1.5334x; 1.5334x over previous
//
#include <hip/hip_runtime.h>

typedef short short8  __attribute__((ext_vector_type(8)));
typedef short short4v __attribute__((ext_vector_type(4)));
typedef float f32x4   __attribute__((ext_vector_type(4)));
typedef int   i32x4   __attribute__((ext_vector_type(4)));

#define NB 4
#define NS 4096
#define NE 1024
#define ND 64

__device__ __forceinline__ short f2bf(float f) {
    unsigned u = __builtin_bit_cast(unsigned, f);
    u = (u + 0x7FFFu + ((u >> 16) & 1u)) >> 16;
    return (short)u;
}
__device__ __forceinline__ float bf2f(short s) {
    unsigned u = ((unsigned)(unsigned short)s) << 16;
    return __builtin_bit_cast(float, u);
}

// ---- kernel 1: W -> FRAGMENT-PACKED bf16 hi/lo (scale folded into W_Q).
//      Layout: wtp[(k>>5)*12 + (n>>4)][lane=((k&31)>>3)*16+(n&15)][q=k&7] short8 —
//      i.e. the exact 16B chunk each MFMA lane consumes, stored at base+lane*16.
//      Turns proj's B-load from a 16-cache-line gather into one coalesced 1KB burst. ----
__global__ void prep_wt(const float* __restrict__ WQ, const float* __restrict__ WK,
                        const float* __restrict__ WV,
                        short* __restrict__ wtp_hi, short* __restrict__ wtp_lo) {
    int idx = blockIdx.x * 256 + threadIdx.x;     // 192*1024
    if (idx >= 192 * NE) return;
    int n = idx >> 10, k = idx & (NE - 1);
    int sel = n >> 6, d = n & 63;
    const float* W = (sel == 0) ? WQ : (sel == 1 ? WK : WV);
    float v = W[k * ND + d];
    if (sel == 0) v *= 0.125f;                    // 1/sqrt(64), exact power of 2
    short hi = f2bf(v);
    short lo = f2bf(v - bf2f(hi));
    int off = ((k >> 5) * 12 + (n >> 4)) * 512 + ((k & 31) >> 3) * 128 + (n & 15) * 8 + (k & 7);
    wtp_hi[off] = hi;
    wtp_lo[off] = lo;
}

// ---- kernel 2: QKV projection — r15 structure (BM=32, 2048 blocks, ping-pong,
//      unroll 1, XCD-pin) + COALESCED packed-B loads (r18 change). ----
__global__ __launch_bounds__(64, 2) void proj_rope(
        const float* __restrict__ x,
        const short* __restrict__ wtp_hi, const short* __restrict__ wtp_lo,
        short* __restrict__ qhi, short* __restrict__ qlo,
        short* __restrict__ khi, short* __restrict__ klo,
        short* __restrict__ vtb) {
    const int lane = threadIdx.x;
    const int g = lane >> 4, cl = lane & 15;
    const int bid = blockIdx.x;
    const int rtile = ((bid >> 5) << 3) | (bid & 7);   // 0..511 (XCD-pin: col-mates +8)
    const int rb = rtile << 5;                         // 32-row tile
    const int c0 = ((bid >> 3) & 3) * 48;              // 48-col tile

    f32x4 acc[2][3];
    #pragma unroll
    for (int i = 0; i < 2; ++i)
        #pragma unroll
        for (int j = 0; j < 3; ++j) acc[i][j] = (f32x4){0.f, 0.f, 0.f, 0.f};

    const float* xb  = x + (size_t)(rb + cl) * NE + (g << 3);
    const short* bph = wtp_hi + (size_t)(c0 >> 4) * 512 + (lane << 3);
    const short* bpl = wtp_lo + (size_t)(c0 >> 4) * 512 + (lane << 3);

    float4 x0[4], x1[4];          // ping-pong x slots: [rt*2 + half]
    short8 b0[6], b1[6];          // ping-pong B slots: [ct*2 + (hi/lo)]

#define LOADX(Xs, kk) {                                                      \
        const float* xp = xb + (kk);                                         \
        Xs[0] = *(const float4*)(xp);                                        \
        Xs[1] = *(const float4*)(xp + 4);                                    \
        Xs[2] = *(const float4*)(xp + (NE << 4));                            \
        Xs[3] = *(const float4*)(xp + (NE << 4) + 4); }
#define LOADB(Bs, kk) {                                                      \
        const int ko = ((kk) >> 5) * 6144;                                   \
        _Pragma("unroll")                                                    \
        for (int ct = 0; ct < 3; ++ct) {                                     \
            Bs[ct * 2]     = *(const short8*)(bph + ko + ct * 512);          \
            Bs[ct * 2 + 1] = *(const short8*)(bpl + ko + ct * 512);          \
        } }
#define STAGE(Xs, Bs) {                                                      \
        short8 ah[2], al[2];                                                 \
        _Pragma("unroll")                                                    \
        for (int rt = 0; rt < 2; ++rt) {                                     \
            float vv[8] = {Xs[rt*2].x, Xs[rt*2].y, Xs[rt*2].z, Xs[rt*2].w,   \
                           Xs[rt*2+1].x, Xs[rt*2+1].y, Xs[rt*2+1].z, Xs[rt*2+1].w}; \
            _Pragma("unroll")                                                \
            for (int q = 0; q < 8; ++q) {                                    \
                short h = f2bf(vv[q]);                                       \
                ah[rt][q] = h;                                               \
                al[rt][q] = f2bf(vv[q] - bf2f(h));                           \
            }                                                                \
        }                                                                    \
        _Pragma("unroll")                                                    \
        for (int ct = 0; ct < 3; ++ct) {                                     \
            _Pragma("unroll")                                                \
            for (int rt = 0; rt < 2; ++rt) {                                 \
                acc[rt][ct] = __builtin_amdgcn_mfma_f32_16x16x32_bf16(ah[rt], Bs[ct*2],   acc[rt][ct], 0, 0, 0); \
                acc[rt][ct] = __builtin_amdgcn_mfma_f32_16x16x32_bf16(ah[rt], Bs[ct*2+1], acc[rt][ct], 0, 0, 0); \
                acc[rt][ct] = __builtin_amdgcn_mfma_f32_16x16x32_bf16(al[rt], Bs[ct*2],   acc[rt][ct], 0, 0, 0); \
            }                                                                \
        } }

    LOADX(x0, 0); LOADX(x1, 32);
    LOADB(b0, 0); LOADB(b1, 32);

    #pragma unroll 1
    for (int k0 = 0; k0 < NE; k0 += 64) {
        STAGE(x0, b0);
        if (k0 + 64 < NE) { LOADX(x0, k0 + 64); LOADB(b0, k0 + 64); }
        STAGE(x1, b1);
        if (k0 + 96 < NE) { LOADX(x1, k0 + 96); LOADB(b1, k0 + 96); }
    }
#undef LOADX
#undef LOADB
#undef STAGE

    // epilogue: RoPE (fp32) + hi/lo split stores (r15, unchanged)
    #pragma unroll
    for (int rt = 0; rt < 2; ++rt) {
        #pragma unroll
        for (int ct = 0; ct < 3; ++ct) {
            int c = c0 + (ct << 4) + cl;
            #pragma unroll
            for (int r = 0; r < 4; ++r) {
                int row = rb + (rt << 4) + (g << 2) + r;
                int s = row & (NS - 1);
                int b = row >> 12;
                float val = acc[rt][ct][r];
                if (c < 128) {
                    int d = c & 63;
                    int p = d >> 1;
                    float freq = exp2f(-(float)p * 0.41524101186091903f);
                    float theta = (float)s * freq;
                    float sn = sinf(theta), cs = cosf(theta);
                    float partner = __shfl_xor(val, 1);
                    float rot = (c & 1) ? fmaf(partner, sn, val * cs)
                                        : fmaf(-partner, sn, val * cs);
                    short hi = f2bf(rot);
                    short lo = f2bf(rot - bf2f(hi));
                    int off = row * ND + d;
                    if (c < 64) { qhi[off] = hi; qlo[off] = lo; }
                    else        { khi[off] = hi; klo[off] = lo; }
                } else {
                    int d = c - 128;
                    vtb[(b << 18) + ((s >> 5) << 11) + (d << 5) + (s & 31)] = f2bf(val);
                }
            }
        }
    }
}

// ---- kernel 3: causal flash attention — UNCHANGED from round 11 (validated, ~30us) ----
__global__ __launch_bounds__(256) void attn_fused(
        const short* __restrict__ qhi, const short* __restrict__ qlo,
        const short* __restrict__ khi, const short* __restrict__ klo,
        const short* __restrict__ vtb, float* __restrict__ outp) {
    __shared__ char sm[54272];
    const int tid = threadIdx.x;
    const int lane = tid & 63, w = tid >> 6;
    const int g = lane >> 4, cl = lane & 15;
    const int bid = blockIdx.x;
    const int b = (bid >> 1) & 3;
    const int t = 255 - (((bid >> 3) << 1) | (bid & 1));
    const int qw = t << 4;
    const int rowb = b << 12;

    char* SW  = sm + w * 12288;
    short* Ps = (short*)(sm + 49152 + w * 1280);

    short8 qh[2], ql[2];
    #pragma unroll
    for (int ks = 0; ks < 2; ++ks) {
        int off = ((rowb + qw + cl) << 6) + (ks << 5) + (g << 3);
        qh[ks] = *(const short8*)(qhi + off);
        ql[ks] = *(const short8*)(qlo + off);
    }

    f32x4 o[4];
    #pragma unroll
    for (int i = 0; i < 4; ++i) o[i] = (f32x4){0.f, 0.f, 0.f, 0.f};
    float m = -1e38f, lsp = 0.f;

    const int nkv = (t >> 1) + 1;
    const short* kpB = khi + (rowb << 6);
    const short* lpB = klo + (rowb << 6);
    const short* vpB = vtb + (b << 18);

    i32x4 stK[4], stL[4], stV[4];
#define ISSUE(jj) {                                                          \
        const short* kp = kpB + ((jj) << 11);                                \
        const short* lp = lpB + ((jj) << 11);                                \
        const short* vp = vpB + ((jj) << 11);                                \
        _Pragma("unroll")                                                    \
        for (int i = 0; i < 4; ++i) {                                        \
            stK[i] = *(const i32x4*)(kp + (lane << 3) + (i << 9));           \
            stL[i] = *(const i32x4*)(lp + (lane << 3) + (i << 9));           \
            stV[i] = *(const i32x4*)(vp + (lane << 3) + (i << 9));           \
        } }

    if (w < nkv) {
        ISSUE(w);
        #pragma unroll 1
        for (int j = w; j < nkv; j += 4) {
            #pragma unroll
            for (int i = 0; i < 4; ++i) {
                int c = lane + (i << 6);
                int kr = c >> 3, kc = c & 7;
                int koff = (kr << 7) + ((kc ^ (kr & 7)) << 4);
                *(i32x4*)(SW + koff) = stK[i];
                *(i32x4*)(SW + 4096 + koff) = stL[i];
                int vr = c >> 2, vc = c & 3;
                *(i32x4*)(SW + 8192 + (vr << 6) + ((vc ^ (vr & 3)) << 4)) = stV[i];
            }
            int jn = j + 4;
            if (jn < nkv) ISSUE(jn);

            f32x4 sc[2];
            #pragma unroll
            for (int ci = 0; ci < 2; ++ci) {
                const int rbase = ((ci << 4) + cl) << 7;
                const int sw = (cl & 7) << 4;
                short8 kh0 = *(short8*)(SW + rbase + (((g << 4)     ) ^ sw));
                short8 kh1 = *(short8*)(SW + rbase + (((g << 4) + 64) ^ sw));
                short8 kl0 = *(short8*)(SW + 4096 + rbase + (((g << 4)     ) ^ sw));
                short8 kl1 = *(short8*)(SW + 4096 + rbase + (((g << 4) + 64) ^ sw));
                f32x4 s = (f32x4){0.f, 0.f, 0.f, 0.f};
                s = __builtin_amdgcn_mfma_f32_16x16x32_bf16(kh0, qh[0], s, 0, 0, 0);
                s = __builtin_amdgcn_mfma_f32_16x16x32_bf16(kh1, qh[1], s, 0, 0, 0);
                s = __builtin_amdgcn_mfma_f32_16x16x32_bf16(kh0, ql[0], s, 0, 0, 0);
                s = __builtin_amdgcn_mfma_f32_16x16x32_bf16(kh1, ql[1], s, 0, 0, 0);
                s = __builtin_amdgcn_mfma_f32_16x16x32_bf16(kl0, qh[0], s, 0, 0, 0);
                s = __builtin_amdgcn_mfma_f32_16x16x32_bf16(kl1, qh[1], s, 0, 0, 0);
                sc[ci] = s;
            }
            if (j == nkv - 1) {
                #pragma unroll
                for (int ci = 0; ci < 2; ++ci)
                    #pragma unroll
                    for (int r = 0; r < 4; ++r)
                        if ((j << 5) + (ci << 4) + (g << 2) + r > qw + cl) sc[ci][r] = -1e30f;
            }
            float pm = fmaxf(fmaxf(fmaxf(sc[0][0], sc[0][1]), fmaxf(sc[0][2], sc[0][3])),
                             fmaxf(fmaxf(sc[1][0], sc[1][1]), fmaxf(sc[1][2], sc[1][3])));
            pm = fmaxf(pm, __shfl_xor(pm, 16));
            pm = fmaxf(pm, __shfl_xor(pm, 32));
            const float mo = m;
            m = fmaxf(m, pm);
            const float rs = __expf(mo - m);
            float psum = 0.f;
            #pragma unroll
            for (int ci = 0; ci < 2; ++ci) {
                float p0 = __expf(sc[ci][0] - m), p1 = __expf(sc[ci][1] - m);
                float p2 = __expf(sc[ci][2] - m), p3 = __expf(sc[ci][3] - m);
                psum += (p0 + p1) + (p2 + p3);
                short4v pk;
                pk[0] = f2bf(p0); pk[1] = f2bf(p1); pk[2] = f2bf(p2); pk[3] = f2bf(p3);
                *(short4v*)(Ps + cl * 40 + (ci << 4) + (g << 2)) = pk;
            }
            lsp = lsp * rs + psum;
            if (__any(m > mo)) {
                float rs4[4];
                #pragma unroll
                for (int r = 0; r < 4; ++r) rs4[r] = __shfl(rs, (g << 2) + r);
                #pragma unroll
                for (int dt = 0; dt < 4; ++dt)
                    #pragma unroll
                    for (int r = 0; r < 4; ++r) o[dt][r] *= rs4[r];
            }
            short8 pa = *(short8*)(Ps + cl * 40 + (g << 3));
            #pragma unroll
            for (int dt = 0; dt < 4; ++dt) {
                int vrow = (dt << 4) + cl;
                short8 vf = *(short8*)(SW + 8192 + (vrow << 6)
                                        + (((g << 4)) ^ ((vrow & 3) << 4)));
                o[dt] = __builtin_amdgcn_mfma_f32_16x16x32_bf16(pa, vf, o[dt], 0, 0, 0);
            }
        }
    }
#undef ISSUE

    {
        float* Co = (float*)SW;
        #pragma unroll
        for (int dt = 0; dt < 4; ++dt)
            #pragma unroll
            for (int r = 0; r < 4; ++r)
                Co[((g << 2) + r) * 66 + (dt << 4) + cl] = o[dt][r];
        lsp += __shfl_xor(lsp, 16);
        lsp += __shfl_xor(lsp, 32);
        if (g == 0) {
            *(float*)(SW + 4224 + (cl << 2)) = m;
            *(float*)(SW + 4288 + (cl << 2)) = lsp;
        }
    }
    __syncthreads();

    if (w == 0) {
        #pragma unroll
        for (int r = 0; r < 4; ++r) {
            const int row = (g << 2) + r;
            float mv[4], lv[4];
            #pragma unroll
            for (int v = 0; v < 4; ++v) {
                mv[v] = *(const float*)(sm + v * 12288 + 4224 + (row << 2));
                lv[v] = *(const float*)(sm + v * 12288 + 4288 + (row << 2));
            }
            float M = fmaxf(fmaxf(mv[0], mv[1]), fmaxf(mv[2], mv[3]));
            float e[4];
            float L = 0.f;
            #pragma unroll
            for (int v = 0; v < 4; ++v) { e[v] = __expf(mv[v] - M); L += lv[v] * e[v]; }
            float inv = 1.f / L;
            #pragma unroll
            for (int dt = 0; dt < 4; ++dt) {
                int d = (dt << 4) + cl;
                float O = 0.f;
                #pragma unroll
                for (int v = 0; v < 4; ++v)
                    O += ((const float*)(sm + v * 12288))[row * 66 + d] * e[v];
                outp[(rowb + qw + row) * ND + d] = O * inv;
            }
        }
    }
}

extern "C" void kernel_launch(void* const* d_in, const int* in_sizes, int n_in,
                              void* d_out, int out_size, void* d_ws, size_t ws_size,
                              hipStream_t stream) {
    const float* x  = (const float*)d_in[0];
    // d_in[1] = mask (int32 tril) -- causal structure known, unused
    const float* WQ = (const float*)d_in[2];
    const float* WK = (const float*)d_in[3];
    const float* WV = (const float*)d_in[4];

    const size_t need = 786432u + 4u * 2097152u + 2097152u;   // 11,272,192 B
    if (ws_size < need) return;

    char* ws = (char*)d_ws;
    short* wtph = (short*)(ws);                                  // packed B frags, 384 KB
    short* wtpl = (short*)(ws + 393216);
    short* qhi  = (short*)(ws + 786432);                         // 2 MB each
    short* qlo  = (short*)(ws + 786432 + 1 * 2097152);
    short* khi  = (short*)(ws + 786432 + 2 * 2097152);
    short* klo  = (short*)(ws + 786432 + 3 * 2097152);
    short* vtb  = (short*)(ws + 786432 + 4 * 2097152);           // V^T tile-blocked [B][128][64][32]

    prep_wt<<<768, 256, 0, stream>>>(WQ, WK, WV, wtph, wtpl);
    proj_rope<<<2048, 64, 0, stream>>>(x, wtph, wtpl, qhi, qlo, khi, klo, vtb);
    attn_fused<<<1024, 256, 0, stream>>>(qhi, qlo, khi, klo, vtb, (float*)d_out);
}

// Round 19
// 93.869 us; speedup vs baseline: 1.9005x; 1.2394x over previous
//
#include <hip/hip_runtime.h>

typedef short short8  __attribute__((ext_vector_type(8)));
typedef short short4v __attribute__((ext_vector_type(4)));
typedef float f32x4   __attribute__((ext_vector_type(4)));
typedef int   i32x4   __attribute__((ext_vector_type(4)));

#define NB 4
#define NS 4096
#define NE 1024
#define ND 64

__device__ __forceinline__ short f2bf(float f) {
    unsigned u = __builtin_bit_cast(unsigned, f);
    u = (u + 0x7FFFu + ((u >> 16) & 1u)) >> 16;
    return (short)u;
}
__device__ __forceinline__ float bf2f(short s) {
    unsigned u = ((unsigned)(unsigned short)s) << 16;
    return __builtin_bit_cast(float, u);
}

// ---- kernel 1: W -> FRAGMENT-PACKED bf16 hi/lo (r18, validated) ----
__global__ void prep_wt(const float* __restrict__ WQ, const float* __restrict__ WK,
                        const float* __restrict__ WV,
                        short* __restrict__ wtp_hi, short* __restrict__ wtp_lo) {
    int idx = blockIdx.x * 256 + threadIdx.x;     // 192*1024
    if (idx >= 192 * NE) return;
    int n = idx >> 10, k = idx & (NE - 1);
    int sel = n >> 6, d = n & 63;
    const float* W = (sel == 0) ? WQ : (sel == 1 ? WK : WV);
    float v = W[k * ND + d];
    if (sel == 0) v *= 0.125f;                    // 1/sqrt(64), exact power of 2
    short hi = f2bf(v);
    short lo = f2bf(v - bf2f(hi));
    int off = ((k >> 5) * 12 + (n >> 4)) * 512 + ((k & 31) >> 3) * 128 + (n & 15) * 8 + (k & 7);
    wtp_hi[off] = hi;
    wtp_lo[off] = lo;
}

// ---- kernel 2: QKV projection — 4-wave blocks, x staged ONCE to LDS (coalesced,
//      hi/lo pre-converted, chunk-XOR swizzle = attn-proven), packed-B coalesced
//      ping-pong regs. Kills the x-gather (r18's last gather) + 4x less x traffic. ----
__global__ __launch_bounds__(256, 2) void proj_rope(
        const float* __restrict__ x,
        const short* __restrict__ wtp_hi, const short* __restrict__ wtp_lo,
        short* __restrict__ qhi, short* __restrict__ qlo,
        short* __restrict__ khi, short* __restrict__ klo,
        short* __restrict__ vtb) {
    __shared__ short Xh[32 * 64], Xl[32 * 64];    // 8KB: 32 rows x 64 k, chunk-XOR swizzled
    const int tid = threadIdx.x;
    const int w = tid >> 6, lane = tid & 63;
    const int g = lane >> 4, cl = lane & 15;
    const int rb = blockIdx.x << 5;               // 32-row tile
    const int c0 = w * 48;                        // wave's 48-col tile

    f32x4 acc[2][3];
    #pragma unroll
    for (int i = 0; i < 2; ++i)
        #pragma unroll
        for (int j = 0; j < 3; ++j) acc[i][j] = (f32x4){0.f, 0.f, 0.f, 0.f};

    // staging map: thread t -> row t>>3, 8-k chunk t&7 (coalesced 32B/thread)
    const int srow = tid >> 3, skc = tid & 7;
    const float* xs0 = x + (size_t)(rb + srow) * NE + (skc << 3);
    const int swoff = srow * 64 + ((skc ^ (srow & 7)) << 3);   // swizzled LDS slot

    const short* bph = wtp_hi + (size_t)(c0 >> 4) * 512 + (lane << 3);
    const short* bpl = wtp_lo + (size_t)(c0 >> 4) * 512 + (lane << 3);

    float4 xr0, xr1;
    short8 b0[6], b1[6];

#define LOADXR(kk) { xr0 = *(const float4*)(xs0 + (kk)); \
                     xr1 = *(const float4*)(xs0 + (kk) + 4); }
#define LOADB(Bs, kk) {                                                      \
        const int ko = ((kk) >> 5) * 6144;                                   \
        _Pragma("unroll")                                                    \
        for (int ct = 0; ct < 3; ++ct) {                                     \
            Bs[ct * 2]     = *(const short8*)(bph + ko + ct * 512);          \
            Bs[ct * 2 + 1] = *(const short8*)(bpl + ko + ct * 512);          \
        } }
// half-h compute: frag chunk = 4h+g, XOR row&7 (matches write swizzle)
#define HALF(h, Bs) {                                                        \
        _Pragma("unroll")                                                    \
        for (int rt = 0; rt < 2; ++rt) {                                     \
            const int R = (rt << 4) + cl;                                    \
            const int ro = R * 64 + ((((h) * 4 + g) ^ (R & 7)) << 3);        \
            short8 ah = *(const short8*)(Xh + ro);                           \
            short8 al = *(const short8*)(Xl + ro);                           \
            _Pragma("unroll")                                                \
            for (int ct = 0; ct < 3; ++ct) {                                 \
                acc[rt][ct] = __builtin_amdgcn_mfma_f32_16x16x32_bf16(ah, Bs[ct*2],   acc[rt][ct], 0, 0, 0); \
                acc[rt][ct] = __builtin_amdgcn_mfma_f32_16x16x32_bf16(ah, Bs[ct*2+1], acc[rt][ct], 0, 0, 0); \
                acc[rt][ct] = __builtin_amdgcn_mfma_f32_16x16x32_bf16(al, Bs[ct*2],   acc[rt][ct], 0, 0, 0); \
            }                                                                \
        } }

    LOADXR(0);
    LOADB(b0, 0);

    #pragma unroll 1
    for (int k0 = 0; k0 < NE; k0 += 64) {
        // convert this iter's staged x to hi/lo (once per block, during staging)
        short8 h8, l8;
        {
            float vv[8] = {xr0.x, xr0.y, xr0.z, xr0.w, xr1.x, xr1.y, xr1.z, xr1.w};
            #pragma unroll
            for (int q = 0; q < 8; ++q) {
                short h = f2bf(vv[q]);
                h8[q] = h;
                l8[q] = f2bf(vv[q] - bf2f(h));
            }
        }
        __syncthreads();                          // prior iter's LDS reads done
        *(short8*)(Xh + swoff) = h8;
        *(short8*)(Xl + swoff) = l8;
        if (k0 + 64 < NE) LOADXR(k0 + 64);        // next x tile (1-iter distance)
        LOADB(b1, k0 + 32);                       // B for half 1
        __syncthreads();                          // stage visible
        HALF(0, b0);
        if (k0 + 64 < NE) LOADB(b0, k0 + 64);     // B for next iter half 0
        HALF(1, b1);
    }
#undef LOADXR
#undef LOADB
#undef HALF

    // epilogue: RoPE (fp32) + hi/lo split stores (per-wave c0, validated logic)
    #pragma unroll
    for (int rt = 0; rt < 2; ++rt) {
        #pragma unroll
        for (int ct = 0; ct < 3; ++ct) {
            int c = c0 + (ct << 4) + cl;
            #pragma unroll
            for (int r = 0; r < 4; ++r) {
                int row = rb + (rt << 4) + (g << 2) + r;
                int s = row & (NS - 1);
                int b = row >> 12;
                float val = acc[rt][ct][r];
                if (c < 128) {
                    int d = c & 63;
                    int p = d >> 1;
                    float freq = exp2f(-(float)p * 0.41524101186091903f);
                    float theta = (float)s * freq;
                    float sn = sinf(theta), cs = cosf(theta);
                    float partner = __shfl_xor(val, 1);
                    float rot = (c & 1) ? fmaf(partner, sn, val * cs)
                                        : fmaf(-partner, sn, val * cs);
                    short hi = f2bf(rot);
                    short lo = f2bf(rot - bf2f(hi));
                    int off = row * ND + d;
                    if (c < 64) { qhi[off] = hi; qlo[off] = lo; }
                    else        { khi[off] = hi; klo[off] = lo; }
                } else {
                    int d = c - 128;
                    vtb[(b << 18) + ((s >> 5) << 11) + (d << 5) + (s & 31)] = f2bf(val);
                }
            }
        }
    }
}

// ---- kernel 3: causal flash attention — UNCHANGED from round 11 (validated, ~30us) ----
__global__ __launch_bounds__(256) void attn_fused(
        const short* __restrict__ qhi, const short* __restrict__ qlo,
        const short* __restrict__ khi, const short* __restrict__ klo,
        const short* __restrict__ vtb, float* __restrict__ outp) {
    __shared__ char sm[54272];
    const int tid = threadIdx.x;
    const int lane = tid & 63, w = tid >> 6;
    const int g = lane >> 4, cl = lane & 15;
    const int bid = blockIdx.x;
    const int b = (bid >> 1) & 3;
    const int t = 255 - (((bid >> 3) << 1) | (bid & 1));
    const int qw = t << 4;
    const int rowb = b << 12;

    char* SW  = sm + w * 12288;
    short* Ps = (short*)(sm + 49152 + w * 1280);

    short8 qh[2], ql[2];
    #pragma unroll
    for (int ks = 0; ks < 2; ++ks) {
        int off = ((rowb + qw + cl) << 6) + (ks << 5) + (g << 3);
        qh[ks] = *(const short8*)(qhi + off);
        ql[ks] = *(const short8*)(qlo + off);
    }

    f32x4 o[4];
    #pragma unroll
    for (int i = 0; i < 4; ++i) o[i] = (f32x4){0.f, 0.f, 0.f, 0.f};
    float m = -1e38f, lsp = 0.f;

    const int nkv = (t >> 1) + 1;
    const short* kpB = khi + (rowb << 6);
    const short* lpB = klo + (rowb << 6);
    const short* vpB = vtb + (b << 18);

    i32x4 stK[4], stL[4], stV[4];
#define ISSUE(jj) {                                                          \
        const short* kp = kpB + ((jj) << 11);                                \
        const short* lp = lpB + ((jj) << 11);                                \
        const short* vp = vpB + ((jj) << 11);                                \
        _Pragma("unroll")                                                    \
        for (int i = 0; i < 4; ++i) {                                        \
            stK[i] = *(const i32x4*)(kp + (lane << 3) + (i << 9));           \
            stL[i] = *(const i32x4*)(lp + (lane << 3) + (i << 9));           \
            stV[i] = *(const i32x4*)(vp + (lane << 3) + (i << 9));           \
        } }

    if (w < nkv) {
        ISSUE(w);
        #pragma unroll 1
        for (int j = w; j < nkv; j += 4) {
            #pragma unroll
            for (int i = 0; i < 4; ++i) {
                int c = lane + (i << 6);
                int kr = c >> 3, kc = c & 7;
                int koff = (kr << 7) + ((kc ^ (kr & 7)) << 4);
                *(i32x4*)(SW + koff) = stK[i];
                *(i32x4*)(SW + 4096 + koff) = stL[i];
                int vr = c >> 2, vc = c & 3;
                *(i32x4*)(SW + 8192 + (vr << 6) + ((vc ^ (vr & 3)) << 4)) = stV[i];
            }
            int jn = j + 4;
            if (jn < nkv) ISSUE(jn);

            f32x4 sc[2];
            #pragma unroll
            for (int ci = 0; ci < 2; ++ci) {
                const int rbase = ((ci << 4) + cl) << 7;
                const int sw = (cl & 7) << 4;
                short8 kh0 = *(short8*)(SW + rbase + (((g << 4)     ) ^ sw));
                short8 kh1 = *(short8*)(SW + rbase + (((g << 4) + 64) ^ sw));
                short8 kl0 = *(short8*)(SW + 4096 + rbase + (((g << 4)     ) ^ sw));
                short8 kl1 = *(short8*)(SW + 4096 + rbase + (((g << 4) + 64) ^ sw));
                f32x4 s = (f32x4){0.f, 0.f, 0.f, 0.f};
                s = __builtin_amdgcn_mfma_f32_16x16x32_bf16(kh0, qh[0], s, 0, 0, 0);
                s = __builtin_amdgcn_mfma_f32_16x16x32_bf16(kh1, qh[1], s, 0, 0, 0);
                s = __builtin_amdgcn_mfma_f32_16x16x32_bf16(kh0, ql[0], s, 0, 0, 0);
                s = __builtin_amdgcn_mfma_f32_16x16x32_bf16(kh1, ql[1], s, 0, 0, 0);
                s = __builtin_amdgcn_mfma_f32_16x16x32_bf16(kl0, qh[0], s, 0, 0, 0);
                s = __builtin_amdgcn_mfma_f32_16x16x32_bf16(kl1, qh[1], s, 0, 0, 0);
                sc[ci] = s;
            }
            if (j == nkv - 1) {
                #pragma unroll
                for (int ci = 0; ci < 2; ++ci)
                    #pragma unroll
                    for (int r = 0; r < 4; ++r)
                        if ((j << 5) + (ci << 4) + (g << 2) + r > qw + cl) sc[ci][r] = -1e30f;
            }
            float pm = fmaxf(fmaxf(fmaxf(sc[0][0], sc[0][1]), fmaxf(sc[0][2], sc[0][3])),
                             fmaxf(fmaxf(sc[1][0], sc[1][1]), fmaxf(sc[1][2], sc[1][3])));
            pm = fmaxf(pm, __shfl_xor(pm, 16));
            pm = fmaxf(pm, __shfl_xor(pm, 32));
            const float mo = m;
            m = fmaxf(m, pm);
            const float rs = __expf(mo - m);
            float psum = 0.f;
            #pragma unroll
            for (int ci = 0; ci < 2; ++ci) {
                float p0 = __expf(sc[ci][0] - m), p1 = __expf(sc[ci][1] - m);
                float p2 = __expf(sc[ci][2] - m), p3 = __expf(sc[ci][3] - m);
                psum += (p0 + p1) + (p2 + p3);
                short4v pk;
                pk[0] = f2bf(p0); pk[1] = f2bf(p1); pk[2] = f2bf(p2); pk[3] = f2bf(p3);
                *(short4v*)(Ps + cl * 40 + (ci << 4) + (g << 2)) = pk;
            }
            lsp = lsp * rs + psum;
            if (__any(m > mo)) {
                float rs4[4];
                #pragma unroll
                for (int r = 0; r < 4; ++r) rs4[r] = __shfl(rs, (g << 2) + r);
                #pragma unroll
                for (int dt = 0; dt < 4; ++dt)
                    #pragma unroll
                    for (int r = 0; r < 4; ++r) o[dt][r] *= rs4[r];
            }
            short8 pa = *(short8*)(Ps + cl * 40 + (g << 3));
            #pragma unroll
            for (int dt = 0; dt < 4; ++dt) {
                int vrow = (dt << 4) + cl;
                short8 vf = *(short8*)(SW + 8192 + (vrow << 6)
                                        + (((g << 4)) ^ ((vrow & 3) << 4)));
                o[dt] = __builtin_amdgcn_mfma_f32_16x16x32_bf16(pa, vf, o[dt], 0, 0, 0);
            }
        }
    }
#undef ISSUE

    {
        float* Co = (float*)SW;
        #pragma unroll
        for (int dt = 0; dt < 4; ++dt)
            #pragma unroll
            for (int r = 0; r < 4; ++r)
                Co[((g << 2) + r) * 66 + (dt << 4) + cl] = o[dt][r];
        lsp += __shfl_xor(lsp, 16);
        lsp += __shfl_xor(lsp, 32);
        if (g == 0) {
            *(float*)(SW + 4224 + (cl << 2)) = m;
            *(float*)(SW + 4288 + (cl << 2)) = lsp;
        }
    }
    __syncthreads();

    if (w == 0) {
        #pragma unroll
        for (int r = 0; r < 4; ++r) {
            const int row = (g << 2) + r;
            float mv[4], lv[4];
            #pragma unroll
            for (int v = 0; v < 4; ++v) {
                mv[v] = *(const float*)(sm + v * 12288 + 4224 + (row << 2));
                lv[v] = *(const float*)(sm + v * 12288 + 4288 + (row << 2));
            }
            float M = fmaxf(fmaxf(mv[0], mv[1]), fmaxf(mv[2], mv[3]));
            float e[4];
            float L = 0.f;
            #pragma unroll
            for (int v = 0; v < 4; ++v) { e[v] = __expf(mv[v] - M); L += lv[v] * e[v]; }
            float inv = 1.f / L;
            #pragma unroll
            for (int dt = 0; dt < 4; ++dt) {
                int d = (dt << 4) + cl;
                float O = 0.f;
                #pragma unroll
                for (int v = 0; v < 4; ++v)
                    O += ((const float*)(sm + v * 12288))[row * 66 + d] * e[v];
                outp[(rowb + qw + row) * ND + d] = O * inv;
            }
        }
    }
}

extern "C" void kernel_launch(void* const* d_in, const int* in_sizes, int n_in,
                              void* d_out, int out_size, void* d_ws, size_t ws_size,
                              hipStream_t stream) {
    const float* x  = (const float*)d_in[0];
    // d_in[1] = mask (int32 tril) -- causal structure known, unused
    const float* WQ = (const float*)d_in[2];
    const float* WK = (const float*)d_in[3];
    const float* WV = (const float*)d_in[4];

    const size_t need = 786432u + 4u * 2097152u + 2097152u;   // 11,272,192 B
    if (ws_size < need) return;

    char* ws = (char*)d_ws;
    short* wtph = (short*)(ws);                                  // packed B frags, 384 KB
    short* wtpl = (short*)(ws + 393216);
    short* qhi  = (short*)(ws + 786432);                         // 2 MB each
    short* qlo  = (short*)(ws + 786432 + 1 * 2097152);
    short* khi  = (short*)(ws + 786432 + 2 * 2097152);
    short* klo  = (short*)(ws + 786432 + 3 * 2097152);
    short* vtb  = (short*)(ws + 786432 + 4 * 2097152);           // V^T tile-blocked [B][128][64][32]

    prep_wt<<<768, 256, 0, stream>>>(WQ, WK, WV, wtph, wtpl);
    proj_rope<<<512, 256, 0, stream>>>(x, wtph, wtpl, qhi, qlo, khi, klo, vtb);
    attn_fused<<<1024, 256, 0, stream>>>(qhi, qlo, khi, klo, vtb, (float*)d_out);
}

// Round 20
// 88.527 us; speedup vs baseline: 2.0152x; 1.0603x over previous
//
#include <hip/hip_runtime.h>

typedef short short8  __attribute__((ext_vector_type(8)));
typedef short short4v __attribute__((ext_vector_type(4)));
typedef float f32x4   __attribute__((ext_vector_type(4)));
typedef int   i32x4   __attribute__((ext_vector_type(4)));

#define NB 4
#define NS 4096
#define NE 1024
#define ND 64

__device__ __forceinline__ short f2bf(float f) {
    unsigned u = __builtin_bit_cast(unsigned, f);
    u = (u + 0x7FFFu + ((u >> 16) & 1u)) >> 16;
    return (short)u;
}
__device__ __forceinline__ float bf2f(short s) {
    unsigned u = ((unsigned)(unsigned short)s) << 16;
    return __builtin_bit_cast(float, u);
}

// ---- kernel 1: W -> FRAGMENT-PACKED bf16 hi/lo (r18, validated) ----
__global__ void prep_wt(const float* __restrict__ WQ, const float* __restrict__ WK,
                        const float* __restrict__ WV,
                        short* __restrict__ wtp_hi, short* __restrict__ wtp_lo) {
    int idx = blockIdx.x * 256 + threadIdx.x;     // 192*1024
    if (idx >= 192 * NE) return;
    int n = idx >> 10, k = idx & (NE - 1);
    int sel = n >> 6, d = n & 63;
    const float* W = (sel == 0) ? WQ : (sel == 1 ? WK : WV);
    float v = W[k * ND + d];
    if (sel == 0) v *= 0.125f;                    // 1/sqrt(64), exact power of 2
    short hi = f2bf(v);
    short lo = f2bf(v - bf2f(hi));
    int off = ((k >> 5) * 12 + (n >> 4)) * 512 + ((k & 31) >> 3) * 128 + (n & 15) * 8 + (k & 7);
    wtp_hi[off] = hi;
    wtp_lo[off] = lo;
}

// ---- kernel 2: QKV projection — r19 validated (block-shared swizzled x LDS stage,
//      packed-B ping-pong). UNCHANGED. ----
__global__ __launch_bounds__(256, 2) void proj_rope(
        const float* __restrict__ x,
        const short* __restrict__ wtp_hi, const short* __restrict__ wtp_lo,
        short* __restrict__ qhi, short* __restrict__ qlo,
        short* __restrict__ khi, short* __restrict__ klo,
        short* __restrict__ vtb) {
    __shared__ short Xh[32 * 64], Xl[32 * 64];    // 8KB: 32 rows x 64 k, chunk-XOR swizzled
    const int tid = threadIdx.x;
    const int w = tid >> 6, lane = tid & 63;
    const int g = lane >> 4, cl = lane & 15;
    const int rb = blockIdx.x << 5;               // 32-row tile
    const int c0 = w * 48;                        // wave's 48-col tile

    f32x4 acc[2][3];
    #pragma unroll
    for (int i = 0; i < 2; ++i)
        #pragma unroll
        for (int j = 0; j < 3; ++j) acc[i][j] = (f32x4){0.f, 0.f, 0.f, 0.f};

    const int srow = tid >> 3, skc = tid & 7;
    const float* xs0 = x + (size_t)(rb + srow) * NE + (skc << 3);
    const int swoff = srow * 64 + ((skc ^ (srow & 7)) << 3);

    const short* bph = wtp_hi + (size_t)(c0 >> 4) * 512 + (lane << 3);
    const short* bpl = wtp_lo + (size_t)(c0 >> 4) * 512 + (lane << 3);

    float4 xr0, xr1;
    short8 b0[6], b1[6];

#define LOADXR(kk) { xr0 = *(const float4*)(xs0 + (kk)); \
                     xr1 = *(const float4*)(xs0 + (kk) + 4); }
#define LOADB(Bs, kk) {                                                      \
        const int ko = ((kk) >> 5) * 6144;                                   \
        _Pragma("unroll")                                                    \
        for (int ct = 0; ct < 3; ++ct) {                                     \
            Bs[ct * 2]     = *(const short8*)(bph + ko + ct * 512);          \
            Bs[ct * 2 + 1] = *(const short8*)(bpl + ko + ct * 512);          \
        } }
#define HALF(h, Bs) {                                                        \
        _Pragma("unroll")                                                    \
        for (int rt = 0; rt < 2; ++rt) {                                     \
            const int R = (rt << 4) + cl;                                    \
            const int ro = R * 64 + ((((h) * 4 + g) ^ (R & 7)) << 3);        \
            short8 ah = *(const short8*)(Xh + ro);                           \
            short8 al = *(const short8*)(Xl + ro);                           \
            _Pragma("unroll")                                                \
            for (int ct = 0; ct < 3; ++ct) {                                 \
                acc[rt][ct] = __builtin_amdgcn_mfma_f32_16x16x32_bf16(ah, Bs[ct*2],   acc[rt][ct], 0, 0, 0); \
                acc[rt][ct] = __builtin_amdgcn_mfma_f32_16x16x32_bf16(ah, Bs[ct*2+1], acc[rt][ct], 0, 0, 0); \
                acc[rt][ct] = __builtin_amdgcn_mfma_f32_16x16x32_bf16(al, Bs[ct*2],   acc[rt][ct], 0, 0, 0); \
            }                                                                \
        } }

    LOADXR(0);
    LOADB(b0, 0);

    #pragma unroll 1
    for (int k0 = 0; k0 < NE; k0 += 64) {
        short8 h8, l8;
        {
            float vv[8] = {xr0.x, xr0.y, xr0.z, xr0.w, xr1.x, xr1.y, xr1.z, xr1.w};
            #pragma unroll
            for (int q = 0; q < 8; ++q) {
                short h = f2bf(vv[q]);
                h8[q] = h;
                l8[q] = f2bf(vv[q] - bf2f(h));
            }
        }
        __syncthreads();
        *(short8*)(Xh + swoff) = h8;
        *(short8*)(Xl + swoff) = l8;
        if (k0 + 64 < NE) LOADXR(k0 + 64);
        LOADB(b1, k0 + 32);
        __syncthreads();
        HALF(0, b0);
        if (k0 + 64 < NE) LOADB(b0, k0 + 64);
        HALF(1, b1);
    }
#undef LOADXR
#undef LOADB
#undef HALF

    #pragma unroll
    for (int rt = 0; rt < 2; ++rt) {
        #pragma unroll
        for (int ct = 0; ct < 3; ++ct) {
            int c = c0 + (ct << 4) + cl;
            #pragma unroll
            for (int r = 0; r < 4; ++r) {
                int row = rb + (rt << 4) + (g << 2) + r;
                int s = row & (NS - 1);
                int b = row >> 12;
                float val = acc[rt][ct][r];
                if (c < 128) {
                    int d = c & 63;
                    int p = d >> 1;
                    float freq = exp2f(-(float)p * 0.41524101186091903f);
                    float theta = (float)s * freq;
                    float sn = sinf(theta), cs = cosf(theta);
                    float partner = __shfl_xor(val, 1);
                    float rot = (c & 1) ? fmaf(partner, sn, val * cs)
                                        : fmaf(-partner, sn, val * cs);
                    short hi = f2bf(rot);
                    short lo = f2bf(rot - bf2f(hi));
                    int off = row * ND + d;
                    if (c < 64) { qhi[off] = hi; qlo[off] = lo; }
                    else        { khi[off] = hi; klo[off] = lo; }
                } else {
                    int d = c - 128;
                    vtb[(b << 18) + ((s >> 5) << 11) + (d << 5) + (s & 31)] = f2bf(val);
                }
            }
        }
    }
}

// ---- kernel 3: causal flash attention — r11 structure; R20 CHANGE: Ps aliased into
//      the Kl stage region (SW+4096). Lifetimes per granule: stage Kl (old Ps dead) ->
//      QK reads Kl -> Ps write (Kl dead) -> PV reads Ps. Same-wave DS in-order +
//      may-alias keeps ordering. LDS 54272 -> 49152 => 3 blocks/CU (+50% TLP). ----
__global__ __launch_bounds__(256) void attn_fused(
        const short* __restrict__ qhi, const short* __restrict__ qlo,
        const short* __restrict__ khi, const short* __restrict__ klo,
        const short* __restrict__ vtb, float* __restrict__ outp) {
    __shared__ char sm[49152];                    // 4 x 12288 stage regions (Ps aliased in)
    const int tid = threadIdx.x;
    const int lane = tid & 63, w = tid >> 6;
    const int g = lane >> 4, cl = lane & 15;
    const int bid = blockIdx.x;
    const int b = (bid >> 1) & 3;
    const int t = 255 - (((bid >> 3) << 1) | (bid & 1));
    const int qw = t << 4;
    const int rowb = b << 12;

    char* SW  = sm + w * 12288;                   // Kh @0, Kl @4096, Vt @8192
    short* Ps = (short*)(SW + 4096);              // aliases Kl rows 0-9 (dead when used)

    short8 qh[2], ql[2];
    #pragma unroll
    for (int ks = 0; ks < 2; ++ks) {
        int off = ((rowb + qw + cl) << 6) + (ks << 5) + (g << 3);
        qh[ks] = *(const short8*)(qhi + off);
        ql[ks] = *(const short8*)(qlo + off);
    }

    f32x4 o[4];
    #pragma unroll
    for (int i = 0; i < 4; ++i) o[i] = (f32x4){0.f, 0.f, 0.f, 0.f};
    float m = -1e38f, lsp = 0.f;

    const int nkv = (t >> 1) + 1;
    const short* kpB = khi + (rowb << 6);
    const short* lpB = klo + (rowb << 6);
    const short* vpB = vtb + (b << 18);

    i32x4 stK[4], stL[4], stV[4];
#define ISSUE(jj) {                                                          \
        const short* kp = kpB + ((jj) << 11);                                \
        const short* lp = lpB + ((jj) << 11);                                \
        const short* vp = vpB + ((jj) << 11);                                \
        _Pragma("unroll")                                                    \
        for (int i = 0; i < 4; ++i) {                                        \
            stK[i] = *(const i32x4*)(kp + (lane << 3) + (i << 9));           \
            stL[i] = *(const i32x4*)(lp + (lane << 3) + (i << 9));           \
            stV[i] = *(const i32x4*)(vp + (lane << 3) + (i << 9));           \
        } }

    if (w < nkv) {
        ISSUE(w);
        #pragma unroll 1
        for (int j = w; j < nkv; j += 4) {
            #pragma unroll
            for (int i = 0; i < 4; ++i) {
                int c = lane + (i << 6);
                int kr = c >> 3, kc = c & 7;
                int koff = (kr << 7) + ((kc ^ (kr & 7)) << 4);
                *(i32x4*)(SW + koff) = stK[i];
                *(i32x4*)(SW + 4096 + koff) = stL[i];
                int vr = c >> 2, vc = c & 3;
                *(i32x4*)(SW + 8192 + (vr << 6) + ((vc ^ (vr & 3)) << 4)) = stV[i];
            }
            int jn = j + 4;
            if (jn < nkv) ISSUE(jn);

            f32x4 sc[2];
            #pragma unroll
            for (int ci = 0; ci < 2; ++ci) {
                const int rbase = ((ci << 4) + cl) << 7;
                const int sw = (cl & 7) << 4;
                short8 kh0 = *(short8*)(SW + rbase + (((g << 4)     ) ^ sw));
                short8 kh1 = *(short8*)(SW + rbase + (((g << 4) + 64) ^ sw));
                short8 kl0 = *(short8*)(SW + 4096 + rbase + (((g << 4)     ) ^ sw));
                short8 kl1 = *(short8*)(SW + 4096 + rbase + (((g << 4) + 64) ^ sw));
                f32x4 s = (f32x4){0.f, 0.f, 0.f, 0.f};
                s = __builtin_amdgcn_mfma_f32_16x16x32_bf16(kh0, qh[0], s, 0, 0, 0);
                s = __builtin_amdgcn_mfma_f32_16x16x32_bf16(kh1, qh[1], s, 0, 0, 0);
                s = __builtin_amdgcn_mfma_f32_16x16x32_bf16(kh0, ql[0], s, 0, 0, 0);
                s = __builtin_amdgcn_mfma_f32_16x16x32_bf16(kh1, ql[1], s, 0, 0, 0);
                s = __builtin_amdgcn_mfma_f32_16x16x32_bf16(kl0, qh[0], s, 0, 0, 0);
                s = __builtin_amdgcn_mfma_f32_16x16x32_bf16(kl1, qh[1], s, 0, 0, 0);
                sc[ci] = s;
            }
            if (j == nkv - 1) {
                #pragma unroll
                for (int ci = 0; ci < 2; ++ci)
                    #pragma unroll
                    for (int r = 0; r < 4; ++r)
                        if ((j << 5) + (ci << 4) + (g << 2) + r > qw + cl) sc[ci][r] = -1e30f;
            }
            float pm = fmaxf(fmaxf(fmaxf(sc[0][0], sc[0][1]), fmaxf(sc[0][2], sc[0][3])),
                             fmaxf(fmaxf(sc[1][0], sc[1][1]), fmaxf(sc[1][2], sc[1][3])));
            pm = fmaxf(pm, __shfl_xor(pm, 16));
            pm = fmaxf(pm, __shfl_xor(pm, 32));
            const float mo = m;
            m = fmaxf(m, pm);
            const float rs = __expf(mo - m);
            float psum = 0.f;
            #pragma unroll
            for (int ci = 0; ci < 2; ++ci) {
                float p0 = __expf(sc[ci][0] - m), p1 = __expf(sc[ci][1] - m);
                float p2 = __expf(sc[ci][2] - m), p3 = __expf(sc[ci][3] - m);
                psum += (p0 + p1) + (p2 + p3);
                short4v pk;
                pk[0] = f2bf(p0); pk[1] = f2bf(p1); pk[2] = f2bf(p2); pk[3] = f2bf(p3);
                *(short4v*)(Ps + cl * 40 + (ci << 4) + (g << 2)) = pk;
            }
            lsp = lsp * rs + psum;
            if (__any(m > mo)) {
                float rs4[4];
                #pragma unroll
                for (int r = 0; r < 4; ++r) rs4[r] = __shfl(rs, (g << 2) + r);
                #pragma unroll
                for (int dt = 0; dt < 4; ++dt)
                    #pragma unroll
                    for (int r = 0; r < 4; ++r) o[dt][r] *= rs4[r];
            }
            short8 pa = *(short8*)(Ps + cl * 40 + (g << 3));
            #pragma unroll
            for (int dt = 0; dt < 4; ++dt) {
                int vrow = (dt << 4) + cl;
                short8 vf = *(short8*)(SW + 8192 + (vrow << 6)
                                        + (((g << 4)) ^ ((vrow & 3) << 4)));
                o[dt] = __builtin_amdgcn_mfma_f32_16x16x32_bf16(pa, vf, o[dt], 0, 0, 0);
            }
        }
    }
#undef ISSUE

    {
        float* Co = (float*)SW;
        #pragma unroll
        for (int dt = 0; dt < 4; ++dt)
            #pragma unroll
            for (int r = 0; r < 4; ++r)
                Co[((g << 2) + r) * 66 + (dt << 4) + cl] = o[dt][r];
        lsp += __shfl_xor(lsp, 16);
        lsp += __shfl_xor(lsp, 32);
        if (g == 0) {
            *(float*)(SW + 4224 + (cl << 2)) = m;
            *(float*)(SW + 4288 + (cl << 2)) = lsp;
        }
    }
    __syncthreads();

    if (w == 0) {
        #pragma unroll
        for (int r = 0; r < 4; ++r) {
            const int row = (g << 2) + r;
            float mv[4], lv[4];
            #pragma unroll
            for (int v = 0; v < 4; ++v) {
                mv[v] = *(const float*)(sm + v * 12288 + 4224 + (row << 2));
                lv[v] = *(const float*)(sm + v * 12288 + 4288 + (row << 2));
            }
            float M = fmaxf(fmaxf(mv[0], mv[1]), fmaxf(mv[2], mv[3]));
            float e[4];
            float L = 0.f;
            #pragma unroll
            for (int v = 0; v < 4; ++v) { e[v] = __expf(mv[v] - M); L += lv[v] * e[v]; }
            float inv = 1.f / L;
            #pragma unroll
            for (int dt = 0; dt < 4; ++dt) {
                int d = (dt << 4) + cl;
                float O = 0.f;
                #pragma unroll
                for (int v = 0; v < 4; ++v)
                    O += ((const float*)(sm + v * 12288))[row * 66 + d] * e[v];
                outp[(rowb + qw + row) * ND + d] = O * inv;
            }
        }
    }
}

extern "C" void kernel_launch(void* const* d_in, const int* in_sizes, int n_in,
                              void* d_out, int out_size, void* d_ws, size_t ws_size,
                              hipStream_t stream) {
    const float* x  = (const float*)d_in[0];
    // d_in[1] = mask (int32 tril) -- causal structure known, unused
    const float* WQ = (const float*)d_in[2];
    const float* WK = (const float*)d_in[3];
    const float* WV = (const float*)d_in[4];

    const size_t need = 786432u + 4u * 2097152u + 2097152u;   // 11,272,192 B
    if (ws_size < need) return;

    char* ws = (char*)d_ws;
    short* wtph = (short*)(ws);                                  // packed B frags, 384 KB
    short* wtpl = (short*)(ws + 393216);
    short* qhi  = (short*)(ws + 786432);                         // 2 MB each
    short* qlo  = (short*)(ws + 786432 + 1 * 2097152);
    short* khi  = (short*)(ws + 786432 + 2 * 2097152);
    short* klo  = (short*)(ws + 786432 + 3 * 2097152);
    short* vtb  = (short*)(ws + 786432 + 4 * 2097152);           // V^T tile-blocked [B][128][64][32]

    prep_wt<<<768, 256, 0, stream>>>(WQ, WK, WV, wtph, wtpl);
    proj_rope<<<512, 256, 0, stream>>>(x, wtph, wtpl, qhi, qlo, khi, klo, vtb);
    attn_fused<<<1024, 256, 0, stream>>>(qhi, qlo, khi, klo, vtb, (float*)d_out);
}

// Round 21
// 81.264 us; speedup vs baseline: 2.1953x; 1.0894x over previous
//
#include <hip/hip_runtime.h>

typedef short short8  __attribute__((ext_vector_type(8)));
typedef short short4v __attribute__((ext_vector_type(4)));
typedef float f32x4   __attribute__((ext_vector_type(4)));

#define NB 4
#define NS 4096
#define NE 1024
#define ND 64

__device__ __forceinline__ short f2bf(float f) {
    unsigned u = __builtin_bit_cast(unsigned, f);
    u = (u + 0x7FFFu + ((u >> 16) & 1u)) >> 16;
    return (short)u;
}
__device__ __forceinline__ float bf2f(short s) {
    unsigned u = ((unsigned)(unsigned short)s) << 16;
    return __builtin_bit_cast(float, u);
}

// ---- kernel 1: W -> FRAGMENT-PACKED bf16 hi/lo (r18, validated) ----
__global__ void prep_wt(const float* __restrict__ WQ, const float* __restrict__ WK,
                        const float* __restrict__ WV,
                        short* __restrict__ wtp_hi, short* __restrict__ wtp_lo) {
    int idx = blockIdx.x * 256 + threadIdx.x;     // 192*1024
    if (idx >= 192 * NE) return;
    int n = idx >> 10, k = idx & (NE - 1);
    int sel = n >> 6, d = n & 63;
    const float* W = (sel == 0) ? WQ : (sel == 1 ? WK : WV);
    float v = W[k * ND + d];
    if (sel == 0) v *= 0.125f;                    // 1/sqrt(64), exact power of 2
    short hi = f2bf(v);
    short lo = f2bf(v - bf2f(hi));
    int off = ((k >> 5) * 12 + (n >> 4)) * 512 + ((k & 31) >> 3) * 128 + (n & 15) * 8 + (k & 7);
    wtp_hi[off] = hi;
    wtp_lo[off] = lo;
}

// ---- kernel 2: QKV projection — r19 structure; R21 CHANGE: K and V stores go to
//      ATTN-FRAGMENT-PACKED layouts (kfp/vfp), so attn needs no K/V LDS staging.
//      K: lane=((d>>3)&3)*16+(s&15), half=d>>5, q=d&7. V: lane=((s>>3)&3)*16+(d&15), q=s&7. ----
__global__ __launch_bounds__(256, 2) void proj_rope(
        const float* __restrict__ x,
        const short* __restrict__ wtp_hi, const short* __restrict__ wtp_lo,
        short* __restrict__ qhi, short* __restrict__ qlo,
        short* __restrict__ kfph, short* __restrict__ kfpl,
        short* __restrict__ vfp) {
    __shared__ short Xh[32 * 64], Xl[32 * 64];    // 8KB: 32 rows x 64 k, chunk-XOR swizzled
    const int tid = threadIdx.x;
    const int w = tid >> 6, lane = tid & 63;
    const int g = lane >> 4, cl = lane & 15;
    const int rb = blockIdx.x << 5;               // 32-row tile
    const int c0 = w * 48;                        // wave's 48-col tile

    f32x4 acc[2][3];
    #pragma unroll
    for (int i = 0; i < 2; ++i)
        #pragma unroll
        for (int j = 0; j < 3; ++j) acc[i][j] = (f32x4){0.f, 0.f, 0.f, 0.f};

    const int srow = tid >> 3, skc = tid & 7;
    const float* xs0 = x + (size_t)(rb + srow) * NE + (skc << 3);
    const int swoff = srow * 64 + ((skc ^ (srow & 7)) << 3);

    const short* bph = wtp_hi + (size_t)(c0 >> 4) * 512 + (lane << 3);
    const short* bpl = wtp_lo + (size_t)(c0 >> 4) * 512 + (lane << 3);

    float4 xr0, xr1;
    short8 b0[6], b1[6];

#define LOADXR(kk) { xr0 = *(const float4*)(xs0 + (kk)); \
                     xr1 = *(const float4*)(xs0 + (kk) + 4); }
#define LOADB(Bs, kk) {                                                      \
        const int ko = ((kk) >> 5) * 6144;                                   \
        _Pragma("unroll")                                                    \
        for (int ct = 0; ct < 3; ++ct) {                                     \
            Bs[ct * 2]     = *(const short8*)(bph + ko + ct * 512);          \
            Bs[ct * 2 + 1] = *(const short8*)(bpl + ko + ct * 512);          \
        } }
#define HALF(h, Bs) {                                                        \
        _Pragma("unroll")                                                    \
        for (int rt = 0; rt < 2; ++rt) {                                     \
            const int R = (rt << 4) + cl;                                    \
            const int ro = R * 64 + ((((h) * 4 + g) ^ (R & 7)) << 3);        \
            short8 ah = *(const short8*)(Xh + ro);                           \
            short8 al = *(const short8*)(Xl + ro);                           \
            _Pragma("unroll")                                                \
            for (int ct = 0; ct < 3; ++ct) {                                 \
                acc[rt][ct] = __builtin_amdgcn_mfma_f32_16x16x32_bf16(ah, Bs[ct*2],   acc[rt][ct], 0, 0, 0); \
                acc[rt][ct] = __builtin_amdgcn_mfma_f32_16x16x32_bf16(ah, Bs[ct*2+1], acc[rt][ct], 0, 0, 0); \
                acc[rt][ct] = __builtin_amdgcn_mfma_f32_16x16x32_bf16(al, Bs[ct*2],   acc[rt][ct], 0, 0, 0); \
            }                                                                \
        } }

    LOADXR(0);
    LOADB(b0, 0);

    #pragma unroll 1
    for (int k0 = 0; k0 < NE; k0 += 64) {
        short8 h8, l8;
        {
            float vv[8] = {xr0.x, xr0.y, xr0.z, xr0.w, xr1.x, xr1.y, xr1.z, xr1.w};
            #pragma unroll
            for (int q = 0; q < 8; ++q) {
                short h = f2bf(vv[q]);
                h8[q] = h;
                l8[q] = f2bf(vv[q] - bf2f(h));
            }
        }
        __syncthreads();
        *(short8*)(Xh + swoff) = h8;
        *(short8*)(Xl + swoff) = l8;
        if (k0 + 64 < NE) LOADXR(k0 + 64);
        LOADB(b1, k0 + 32);
        __syncthreads();
        HALF(0, b0);
        if (k0 + 64 < NE) LOADB(b0, k0 + 64);
        HALF(1, b1);
    }
#undef LOADXR
#undef LOADB
#undef HALF

    // epilogue: RoPE (fp32) + stores: Q row-major hi/lo, K/V fragment-packed
    #pragma unroll
    for (int rt = 0; rt < 2; ++rt) {
        #pragma unroll
        for (int ct = 0; ct < 3; ++ct) {
            int c = c0 + (ct << 4) + cl;
            #pragma unroll
            for (int r = 0; r < 4; ++r) {
                int row = rb + (rt << 4) + (g << 2) + r;
                int s = row & (NS - 1);
                int b = row >> 12;
                float val = acc[rt][ct][r];
                if (c < 128) {
                    int d = c & 63;
                    int p = d >> 1;
                    float freq = exp2f(-(float)p * 0.41524101186091903f);
                    float theta = (float)s * freq;
                    float sn = sinf(theta), cs = cosf(theta);
                    float partner = __shfl_xor(val, 1);
                    float rot = (c & 1) ? fmaf(partner, sn, val * cs)
                                        : fmaf(-partner, sn, val * cs);
                    short hi = f2bf(rot);
                    short lo = f2bf(rot - bf2f(hi));
                    if (c < 64) {
                        int off = row * ND + d;
                        qhi[off] = hi; qlo[off] = lo;
                    } else {
                        // K fragment-pack
                        int off = ((b << 7) + (s >> 5)) * 2048 + ((s >> 4) & 1) * 1024
                                + (d >> 5) * 512 + (((d >> 3) & 3) * 16 + (s & 15)) * 8 + (d & 7);
                        kfph[off] = hi; kfpl[off] = lo;
                    }
                } else {
                    int d = c - 128;
                    // V fragment-pack
                    int off = ((b << 7) + (s >> 5)) * 2048 + (d >> 4) * 512
                            + (((s >> 3) & 3) * 16 + (d & 15)) * 8 + (s & 7);
                    vfp[off] = f2bf(val);
                }
            }
        }
    }
}

// ---- kernel 3: causal flash attention — R21: K/V read as fragment-packed coalesced
//      1KB bursts straight into MFMA operands; NO K/V LDS staging; only Ps round-trip. ----
__global__ __launch_bounds__(256, 4) void attn_fused(
        const short* __restrict__ qhi, const short* __restrict__ qlo,
        const short* __restrict__ kfph, const short* __restrict__ kfpl,
        const short* __restrict__ vfp, float* __restrict__ outp) {
    __shared__ short Ps[4][16][40];
    __shared__ float Co[4][16][66];
    __shared__ float Cm[4][16], Cls[4][16];
    const int tid = threadIdx.x;
    const int lane = tid & 63, w = tid >> 6;
    const int g = lane >> 4, cl = lane & 15;
    const int bid = blockIdx.x;
    const int b = (bid >> 1) & 3;
    const int t = 255 - (((bid >> 3) << 1) | (bid & 1));   // heavy tiles first
    const int qw = t << 4;
    const int rowb = b << 12;

    short8 qh[2], ql[2];
    #pragma unroll
    for (int ks = 0; ks < 2; ++ks) {
        int off = ((rowb + qw + cl) << 6) + (ks << 5) + (g << 3);
        qh[ks] = *(const short8*)(qhi + off);
        ql[ks] = *(const short8*)(qlo + off);
    }

    f32x4 o[4];
    #pragma unroll
    for (int i = 0; i < 4; ++i) o[i] = (f32x4){0.f, 0.f, 0.f, 0.f};
    float m = -1e38f, lsp = 0.f;

    const int nkv = (t >> 1) + 1;                 // 32-wide kv tiles
    const short* kbaseh = kfph + (size_t)(b << 7) * 2048 + (lane << 3);
    const short* kbasel = kfpl + (size_t)(b << 7) * 2048 + (lane << 3);
    const short* vbase  = vfp  + (size_t)(b << 7) * 2048 + (lane << 3);

    short8 kf[2][4];   // [ci][kh0,kh1,kl0,kl1]
    short8 vf[4];      // [dt]

#define LOADK(jj) {                                                          \
        _Pragma("unroll")                                                    \
        for (int ci = 0; ci < 2; ++ci) {                                     \
            const short* kh = kbaseh + (jj) * 2048 + ci * 1024;              \
            const short* kl = kbasel + (jj) * 2048 + ci * 1024;              \
            kf[ci][0] = *(const short8*)(kh);                                \
            kf[ci][1] = *(const short8*)(kh + 512);                          \
            kf[ci][2] = *(const short8*)(kl);                                \
            kf[ci][3] = *(const short8*)(kl + 512);                          \
        } }
#define LOADV(jj) {                                                          \
        _Pragma("unroll")                                                    \
        for (int dt = 0; dt < 4; ++dt)                                       \
            vf[dt] = *(const short8*)(vbase + (jj) * 2048 + dt * 512);       \
        }

    if (w < nkv) {
        LOADK(w); LOADV(w);
        #pragma unroll 1
        for (int j = w; j < nkv; j += 4) {
            // QK^T (swapped operands): sc[ci][r] = S[kv=(ci<<4)+(g<<2)+r][q=cl]
            f32x4 sc[2];
            #pragma unroll
            for (int ci = 0; ci < 2; ++ci) {
                f32x4 s = (f32x4){0.f, 0.f, 0.f, 0.f};
                s = __builtin_amdgcn_mfma_f32_16x16x32_bf16(kf[ci][0], qh[0], s, 0, 0, 0);
                s = __builtin_amdgcn_mfma_f32_16x16x32_bf16(kf[ci][1], qh[1], s, 0, 0, 0);
                s = __builtin_amdgcn_mfma_f32_16x16x32_bf16(kf[ci][0], ql[0], s, 0, 0, 0);
                s = __builtin_amdgcn_mfma_f32_16x16x32_bf16(kf[ci][1], ql[1], s, 0, 0, 0);
                s = __builtin_amdgcn_mfma_f32_16x16x32_bf16(kf[ci][2], qh[0], s, 0, 0, 0);
                s = __builtin_amdgcn_mfma_f32_16x16x32_bf16(kf[ci][3], qh[1], s, 0, 0, 0);
                sc[ci] = s;
            }
            const int jn = j + 4;
            if (jn < nkv) LOADK(jn);              // refill K frags (consumed above)

            if (j == nkv - 1) {
                #pragma unroll
                for (int ci = 0; ci < 2; ++ci)
                    #pragma unroll
                    for (int r = 0; r < 4; ++r)
                        if ((j << 5) + (ci << 4) + (g << 2) + r > qw + cl) sc[ci][r] = -1e30f;
            }
            // lane-local softmax (row q=cl) + 2 cross-g shfls
            float pm = fmaxf(fmaxf(fmaxf(sc[0][0], sc[0][1]), fmaxf(sc[0][2], sc[0][3])),
                             fmaxf(fmaxf(sc[1][0], sc[1][1]), fmaxf(sc[1][2], sc[1][3])));
            pm = fmaxf(pm, __shfl_xor(pm, 16));
            pm = fmaxf(pm, __shfl_xor(pm, 32));
            const float mo = m;
            m = fmaxf(m, pm);
            const float rs = __expf(mo - m);
            float psum = 0.f;
            #pragma unroll
            for (int ci = 0; ci < 2; ++ci) {
                float p0 = __expf(sc[ci][0] - m), p1 = __expf(sc[ci][1] - m);
                float p2 = __expf(sc[ci][2] - m), p3 = __expf(sc[ci][3] - m);
                psum += (p0 + p1) + (p2 + p3);
                short4v pk;
                pk[0] = f2bf(p0); pk[1] = f2bf(p1); pk[2] = f2bf(p2); pk[3] = f2bf(p3);
                *(short4v*)(&Ps[w][cl][(ci << 4) + (g << 2)]) = pk;
            }
            lsp = lsp * rs + psum;
            if (__any(m > mo)) {
                float rs4[4];
                #pragma unroll
                for (int r = 0; r < 4; ++r) rs4[r] = __shfl(rs, (g << 2) + r);
                #pragma unroll
                for (int dt = 0; dt < 4; ++dt)
                    #pragma unroll
                    for (int r = 0; r < 4; ++r) o[dt][r] *= rs4[r];
            }
            // PV: A = P rows (q), B = V frags (direct from registers)
            short8 pa = *(short8*)(&Ps[w][cl][g << 3]);
            #pragma unroll
            for (int dt = 0; dt < 4; ++dt)
                o[dt] = __builtin_amdgcn_mfma_f32_16x16x32_bf16(pa, vf[dt], o[dt], 0, 0, 0);
            if (jn < nkv) LOADV(jn);              // refill V frags (consumed above)
        }
    }
#undef LOADK
#undef LOADV

    // publish partials (idle waves: m=-1e38, lsp=0 -> zero weight)
    lsp += __shfl_xor(lsp, 16);
    lsp += __shfl_xor(lsp, 32);
    if (g == 0) { Cm[w][cl] = m; Cls[w][cl] = lsp; }
    #pragma unroll
    for (int dt = 0; dt < 4; ++dt)
        #pragma unroll
        for (int r = 0; r < 4; ++r)
            Co[w][(g << 2) + r][(dt << 4) + cl] = o[dt][r];
    __syncthreads();

    // exact flash-combine by wave 0
    if (w == 0) {
        #pragma unroll
        for (int r = 0; r < 4; ++r) {
            const int row = (g << 2) + r;
            float M = fmaxf(fmaxf(Cm[0][row], Cm[1][row]), fmaxf(Cm[2][row], Cm[3][row]));
            float e0 = __expf(Cm[0][row] - M), e1 = __expf(Cm[1][row] - M);
            float e2 = __expf(Cm[2][row] - M), e3 = __expf(Cm[3][row] - M);
            float L = Cls[0][row] * e0 + Cls[1][row] * e1 + Cls[2][row] * e2 + Cls[3][row] * e3;
            float inv = 1.f / L;
            #pragma unroll
            for (int dt = 0; dt < 4; ++dt) {
                int d = (dt << 4) + cl;
                float O = Co[0][row][d] * e0 + Co[1][row][d] * e1
                        + Co[2][row][d] * e2 + Co[3][row][d] * e3;
                outp[(rowb + qw + row) * ND + d] = O * inv;
            }
        }
    }
}

extern "C" void kernel_launch(void* const* d_in, const int* in_sizes, int n_in,
                              void* d_out, int out_size, void* d_ws, size_t ws_size,
                              hipStream_t stream) {
    const float* x  = (const float*)d_in[0];
    // d_in[1] = mask (int32 tril) -- causal structure known, unused
    const float* WQ = (const float*)d_in[2];
    const float* WK = (const float*)d_in[3];
    const float* WV = (const float*)d_in[4];

    const size_t need = 786432u + 5u * 2097152u;   // 11,272,192 B (proven available)
    if (ws_size < need) return;

    char* ws = (char*)d_ws;
    short* wtph = (short*)(ws);                                  // packed B frags, 384 KB
    short* wtpl = (short*)(ws + 393216);
    short* qhi  = (short*)(ws + 786432);                         // 2 MB each
    short* qlo  = (short*)(ws + 786432 + 1 * 2097152);
    short* kfph = (short*)(ws + 786432 + 2 * 2097152);           // K frag-packed hi
    short* kfpl = (short*)(ws + 786432 + 3 * 2097152);           // K frag-packed lo
    short* vfp  = (short*)(ws + 786432 + 4 * 2097152);           // V frag-packed

    prep_wt<<<768, 256, 0, stream>>>(WQ, WK, WV, wtph, wtpl);
    proj_rope<<<512, 256, 0, stream>>>(x, wtph, wtpl, qhi, qlo, kfph, kfpl, vfp);
    attn_fused<<<1024, 256, 0, stream>>>(qhi, qlo, kfph, kfpl, vfp, (float*)d_out);
}